// Round 7
// baseline (400.735 us; speedup 1.0000x reference)
//
#include <hip/hip_runtime.h>
#include <hip/hip_bf16.h>
#include <cstdint>
#include <cstddef>

#define D_MODEL 1024
#define N_HEADS 16
#define D_STATE 64
#define SEQ 4096
#define BATCH 4
#define M_TOK (BATCH * SEQ)          // 16384 tokens
#define N1 4096                      // fused [Wg | p] output width
#define CLEN 32                      // scan chunk length
#define NCH (SEQ / CLEN)             // 128 chunks per sequence
#define NCHAN (BATCH * D_MODEL)      // 4096 scan channels

typedef __attribute__((ext_vector_type(8))) short bf16x8;
typedef __attribute__((ext_vector_type(4))) short bf16x4;
typedef __attribute__((ext_vector_type(4))) float f32x4;

__device__ __forceinline__ float sigmoidf_(float x) {
    return 1.0f / (1.0f + __expf(-x));
}
__device__ __forceinline__ float b2f(short s) {
    union { float f; unsigned u; } v; v.u = ((unsigned)(unsigned short)s) << 16;
    return v.f;
}
__device__ __forceinline__ short f2b(float f) {
    __hip_bfloat16 h = __float2bfloat16(f);
    return *(short*)&h;
}

__device__ __forceinline__ void async_load16(const void* g, void* l) {
    __builtin_amdgcn_global_load_lds(
        (__attribute__((address_space(1))) void*)(g),
        (__attribute__((address_space(3))) void*)(l), 16, 0, 0);
}

// ---------------- fused prep: 3 weight transposes + RMSNorm ----------------
// blocks [0,1024): Wg -> W1T rows 0..1023
// blocks [1024,4096): Wp -> W1T rows 1024..4095, col-permuted to block
//     layout: orig col n = h*192 + t*64 + d -> row 1024 + t*1024 + h*64 + d.
// blocks [4096,5120): Wo -> WoT
// blocks [5120,9216): rmsnorm, 4 rows/block, wave-per-row.
//     R6 BUG FIX: each lane now processes 4 float4s (stride 64) = 16
//     floats, covering the full 1024-element row (R6 covered only 1/4).
__global__ __launch_bounds__(256) void prep_kernel(
    const float* __restrict__ Wg, const float* __restrict__ Wp,
    const float* __restrict__ Wo,
    const float* __restrict__ x, const float* __restrict__ norm_w,
    __hip_bfloat16* __restrict__ W1T, __hip_bfloat16* __restrict__ WoT,
    __hip_bfloat16* __restrict__ xn)
{
    __shared__ float tile[32][33];
    const int bid = blockIdx.x;
    const int tid = threadIdx.x;

    if (bid < 5120) {
        const float* src; __hip_bfloat16* dst; int N, bx, by, perm;
        if (bid < 1024)      { src = Wg; dst = W1T; N = 1024; bx = bid & 31;        by = bid >> 5;        perm = 0; }
        else if (bid < 4096) { int l = bid - 1024; src = Wp; dst = W1T; N = 3072; bx = l % 96; by = l / 96; perm = 1; }
        else                 { int l = bid - 4096; src = Wo; dst = WoT; N = 1024; bx = l & 31; by = l >> 5; perm = 0; }
        int n0 = bx * 32, k0 = by * 32;
        int tx = tid & 31, ty = tid >> 5;
#pragma unroll
        for (int j = 0; j < 32; j += 8)
            tile[ty + j][tx] = src[(size_t)(k0 + ty + j) * N + n0 + tx];
        __syncthreads();
#pragma unroll
        for (int j = 0; j < 32; j += 8) {
            int n = n0 + ty + j;
            int row;
            if (perm) {
                int ht = n >> 6;                  // h*3 + t
                row = 1024 + (ht % 3) * 1024 + (ht / 3) * 64 + (n & 63);
            } else row = n;
            dst[(size_t)row * D_MODEL + k0 + tx] = __float2bfloat16(tile[tx][ty + j]);
        }
    } else {
        // wave-per-row RMSNorm: 4 rows per 256-thread block, 16 floats/lane
        int m = (bid - 5120) * 4 + (tid >> 6);
        int lane = tid & 63;
        const float4* xr = (const float4*)(x + (size_t)m * D_MODEL);
        float4 v[4];
        float ss = 0.f;
#pragma unroll
        for (int q = 0; q < 4; ++q) {
            v[q] = xr[lane + 64 * q];
            ss += v[q].x * v[q].x + v[q].y * v[q].y + v[q].z * v[q].z + v[q].w * v[q].w;
        }
#pragma unroll
        for (int o = 32; o >= 1; o >>= 1) ss += __shfl_xor(ss, o, 64);
        float scale = rsqrtf(ss * (1.0f / D_MODEL) + 1e-6f);
        const float4* wr = (const float4*)norm_w;
#pragma unroll
        for (int q = 0; q < 4; ++q) {
            float4 wv = wr[lane + 64 * q];
            __hip_bfloat16 o4[4];
            o4[0] = __float2bfloat16(wv.x * v[q].x * scale);
            o4[1] = __float2bfloat16(wv.y * v[q].y * scale);
            o4[2] = __float2bfloat16(wv.z * v[q].z * scale);
            o4[3] = __float2bfloat16(wv.w * v[q].w * scale);
            *(uint64_t*)(xn + (size_t)m * D_MODEL + (lane + 64 * q) * 4) = *(uint64_t*)o4;
        }
    }
}

// ---------------- 256x256 deep-pipelined bf16 MFMA GEMM ----------------
// C = A(M,K) * Bt(N,K)^T, 512 threads = 8 waves (2M x 4N), BK=64.
// LDS 128 KiB: 2 dbuf. R6 schedule = R4 read-ahead + DEEP staging:
//   - ONE barrier + ONE vmcnt gate per tile (at P3).
//   - Stage all 8 chunks of tile t+2 at P3(t), right after the barrier,
//     into buf(t). Safety: every wave's buf(t) ds_reads are consumed by
//     its P1/P2 MFMAs (lgkm-drained) before it reaches the P3 barrier,
//     so post-barrier overwrite is race-free; P3's own MFMA uses regs.
//   - Gate vmcnt(0) at P3(t) drains tile t+1's chunks issued at P3(t-1)
//     = 4 phases (~1300 cy) earlier -> HBM latency fully covered.
//   - Read-ahead at P3(t): afA/b0 of t+1 from buf(t+1) (gate-validated,
//     post-barrier so all waves' deposits are visible).
// T2 swizzle (0 conflicts), T1 XCD swizzle, T5 setprio unchanged.
// MODE 0: out bf16, bias = (col<1024 ? bg[col] : bp[perm(col-1024)])
// MODE 1: out fp32, bias = bias0[col] + bias1[row*1024+col] (residual)
template <int MODE>
__global__ __launch_bounds__(512, 2) void gemm256(
    const __hip_bfloat16* __restrict__ A,
    const __hip_bfloat16* __restrict__ Bt,
    const float* __restrict__ bias0,
    const float* __restrict__ bias1,
    void* __restrict__ outp, int N, int K)
{
    extern __shared__ short lds[];
    const int tid = threadIdx.x;
    const int wave = tid >> 6, lane = tid & 63;
    const int fr = lane & 15, fq = lane >> 4;
    const int frx = fr & 7;
    const int wm = (wave >> 2) * 128;   // 2 M-halves of waves
    const int wn = (wave & 3) * 64;     // 4 N-quarters

    // bijective XCD swizzle (nwg % 8 == 0 for both modes)
    const int gx = gridDim.x;
    const int nwg = gx * gridDim.y;
    const int orig = blockIdx.y * gx + blockIdx.x;
    const int swz = (orig & 7) * (nwg >> 3) + (orig >> 3);
    const int m0 = (swz / gx) * 256;
    const int n0 = (swz % gx) * 256;

    // staging map: thread t -> row rb (8 threads/row), 16B slot p8.
    // global source slot pre-inverse-swizzled; LDS dest stays linear.
    const int rb = tid >> 3, p8 = tid & 7;
    const int lsl = p8 ^ (rb & 7);
    const short* Ag0 = (const short*)A + (size_t)(m0 + rb) * K + lsl * 8;
    const short* Bg0 = (const short*)Bt + (size_t)(n0 + rb) * K + lsl * 8;
    const int stL = rb * 64 + p8 * 8;

    // per-lane ds_read byte-address components
    const int laneA = (wm + fr) * 128;
    const int laneB = (wn + fr) * 128;
    const int F0 = (fq ^ frx) * 16;
    const int F1 = ((4 + fq) ^ frx) * 16;

    const int NT = K >> 6;              // K-tiles of 64

    f32x4 acc[2][4][4];
#pragma unroll
    for (int h = 0; h < 2; ++h)
#pragma unroll
        for (int i = 0; i < 4; ++i)
#pragma unroll
            for (int j = 0; j < 4; ++j)
                acc[h][i][j] = (f32x4){0.f, 0.f, 0.f, 0.f};

#define STAGE8(Tt, base)                                                   \
    {                                                                      \
        short* la_ = (base);                                               \
        short* lb_ = (base) + 16384;                                       \
        const short* Ag_ = Ag0 + (size_t)(Tt) * 64;                        \
        const short* Bg_ = Bg0 + (size_t)(Tt) * 64;                        \
        async_load16(Bg_ + (size_t)(0 * 64) * K, lb_ + stL + 0 * 4096);    \
        async_load16(Bg_ + (size_t)(1 * 64) * K, lb_ + stL + 1 * 4096);    \
        async_load16(Bg_ + (size_t)(2 * 64) * K, lb_ + stL + 2 * 4096);    \
        async_load16(Bg_ + (size_t)(3 * 64) * K, lb_ + stL + 3 * 4096);    \
        async_load16(Ag_ + (size_t)(0 * 64) * K, la_ + stL + 0 * 4096);    \
        async_load16(Ag_ + (size_t)(1 * 64) * K, la_ + stL + 1 * 4096);    \
        async_load16(Ag_ + (size_t)(2 * 64) * K, la_ + stL + 2 * 4096);    \
        async_load16(Ag_ + (size_t)(3 * 64) * K, la_ + stL + 3 * 4096);    \
    }
#define RD(base, off) (*(const bf16x8*)((base) + (off)))

    // prologue: stage tile0 -> buf0, tile1 -> buf1; gate tile0; read P0 frags
    STAGE8(0, lds);
    STAGE8(1, lds + 32768);
    asm volatile("s_waitcnt vmcnt(8)" ::: "memory");  // tile0's 8 landed
    __builtin_amdgcn_s_barrier();
    __builtin_amdgcn_sched_barrier(0);

    bf16x8 afA[4][2], afB[4][2], b0[2][2], b1[2][2];
    {
        const char* bA0 = (const char*)lds + laneA + F0;
        const char* bA1 = (const char*)lds + laneA + F1;
        const char* bB0 = (const char*)(lds + 16384) + laneB + F0;
        const char* bB1 = (const char*)(lds + 16384) + laneB + F1;
#pragma unroll
        for (int i = 0; i < 4; ++i) { afA[i][0] = RD(bA0, i * 2048); afA[i][1] = RD(bA1, i * 2048); }
#pragma unroll
        for (int j = 0; j < 2; ++j) { b0[j][0] = RD(bB0, j * 2048); b0[j][1] = RD(bB1, j * 2048); }
    }

    for (int t = 0; t < NT; ++t) {
        const int par = t & 1;
        const short* Ab = lds + (par ? 32768 : 0);
        const short* Bb = Ab + 16384;
        const char* bA0 = (const char*)Ab + laneA + F0;
        const char* bA1 = (const char*)Ab + laneA + F1;
        const char* bB0 = (const char*)Bb + laneB + F0;
        const char* bB1 = (const char*)Bb + laneB + F1;
        const bool pf = (t + 1 < NT);
        const bool pf2 = (t + 2 < NT);

        // ---- P0: read b1(t) ; MFMA h0 x b0 ----
#pragma unroll
        for (int j = 0; j < 2; ++j) { b1[j][0] = RD(bB0, (2 + j) * 2048); b1[j][1] = RD(bB1, (2 + j) * 2048); }
        __builtin_amdgcn_s_setprio(1);
#pragma unroll
        for (int i = 0; i < 4; ++i)
#pragma unroll
            for (int j = 0; j < 2; ++j) {
                acc[0][i][j] = __builtin_amdgcn_mfma_f32_16x16x32_bf16(afA[i][0], b0[j][0], acc[0][i][j], 0, 0, 0);
                acc[0][i][j] = __builtin_amdgcn_mfma_f32_16x16x32_bf16(afA[i][1], b0[j][1], acc[0][i][j], 0, 0, 0);
            }
        __builtin_amdgcn_s_setprio(0);
        __builtin_amdgcn_sched_barrier(0);

        // ---- P1: read afB(t) ; MFMA h0 x b1 ----
#pragma unroll
        for (int i = 0; i < 4; ++i) { afB[i][0] = RD(bA0, 8192 + i * 2048); afB[i][1] = RD(bA1, 8192 + i * 2048); }
        __builtin_amdgcn_s_setprio(1);
#pragma unroll
        for (int i = 0; i < 4; ++i)
#pragma unroll
            for (int j = 0; j < 2; ++j) {
                acc[0][i][2 + j] = __builtin_amdgcn_mfma_f32_16x16x32_bf16(afA[i][0], b1[j][0], acc[0][i][2 + j], 0, 0, 0);
                acc[0][i][2 + j] = __builtin_amdgcn_mfma_f32_16x16x32_bf16(afA[i][1], b1[j][1], acc[0][i][2 + j], 0, 0, 0);
            }
        __builtin_amdgcn_s_setprio(0);
        __builtin_amdgcn_sched_barrier(0);

        // ---- P2: MFMA h1 x b0 ----
        __builtin_amdgcn_s_setprio(1);
#pragma unroll
        for (int i = 0; i < 4; ++i)
#pragma unroll
            for (int j = 0; j < 2; ++j) {
                acc[1][i][j] = __builtin_amdgcn_mfma_f32_16x16x32_bf16(afB[i][0], b0[j][0], acc[1][i][j], 0, 0, 0);
                acc[1][i][j] = __builtin_amdgcn_mfma_f32_16x16x32_bf16(afB[i][1], b0[j][1], acc[1][i][j], 0, 0, 0);
            }
        __builtin_amdgcn_s_setprio(0);
        __builtin_amdgcn_sched_barrier(0);

        // ---- P3: gate ; barrier ; stage t+2 -> buf(t) ; read-ahead t+1 ;
        //          MFMA h1 x b1 ----
        if (pf) {
            asm volatile("s_waitcnt vmcnt(0)" ::: "memory");  // t+1 chunks (4 phases old) landed
            __builtin_amdgcn_s_barrier();                     // all waves: buf(t) reads done, deposits visible
            __builtin_amdgcn_sched_barrier(0);
            if (pf2) STAGE8(t + 2, lds + (par ? 32768 : 0));
            const char* nA0 = (const char*)(lds + (par ? 0 : 32768)) + laneA + F0;
            const char* nA1 = (const char*)(lds + (par ? 0 : 32768)) + laneA + F1;
            const char* nB0 = (const char*)(lds + (par ? 16384 : 49152)) + laneB + F0;
            const char* nB1 = (const char*)(lds + (par ? 16384 : 49152)) + laneB + F1;
#pragma unroll
            for (int i = 0; i < 4; ++i) { afA[i][0] = RD(nA0, i * 2048); afA[i][1] = RD(nA1, i * 2048); }
#pragma unroll
            for (int j = 0; j < 2; ++j) { b0[j][0] = RD(nB0, j * 2048); b0[j][1] = RD(nB1, j * 2048); }
        } else {
            asm volatile("s_waitcnt vmcnt(0)" ::: "memory");
        }
        __builtin_amdgcn_s_setprio(1);
#pragma unroll
        for (int i = 0; i < 4; ++i)
#pragma unroll
            for (int j = 0; j < 2; ++j) {
                acc[1][i][2 + j] = __builtin_amdgcn_mfma_f32_16x16x32_bf16(afB[i][0], b1[j][0], acc[1][i][2 + j], 0, 0, 0);
                acc[1][i][2 + j] = __builtin_amdgcn_mfma_f32_16x16x32_bf16(afB[i][1], b1[j][1], acc[1][i][2 + j], 0, 0, 0);
            }
        __builtin_amdgcn_s_setprio(0);
        __builtin_amdgcn_sched_barrier(0);
    }
#undef RD
#undef STAGE8

    // epilogue: C/D layout row=fq*4+r, col=fr within 16x16 (m89-verified)
    if constexpr (MODE == 0) {
        __hip_bfloat16* O = (__hip_bfloat16*)outp;
        float bv[4];
#pragma unroll
        for (int j = 0; j < 4; ++j) {
            int gcol = n0 + wn + j * 16 + fr;
            if (gcol < D_MODEL) bv[j] = bias0[gcol];
            else {
                int q = gcol - D_MODEL;
                int tt = q >> 10, hd = q & 1023;
                bv[j] = bias1[(hd >> 6) * 192 + tt * 64 + (hd & 63)];
            }
        }
#pragma unroll
        for (int h = 0; h < 2; ++h)
#pragma unroll
            for (int i = 0; i < 4; ++i)
#pragma unroll
                for (int r = 0; r < 4; ++r) {
                    int grow = m0 + wm + h * 64 + i * 16 + fq * 4 + r;
                    __hip_bfloat16* orow = O + (size_t)grow * N + n0 + wn + fr;
#pragma unroll
                    for (int j = 0; j < 4; ++j)
                        orow[j * 16] = __float2bfloat16(acc[h][i][j][r] + bv[j]);
                }
    } else {
        float* O = (float*)outp;
#pragma unroll
        for (int h = 0; h < 2; ++h)
#pragma unroll
            for (int i = 0; i < 4; ++i)
#pragma unroll
                for (int r = 0; r < 4; ++r) {
                    int grow = m0 + wm + h * 64 + i * 16 + fq * 4 + r;
#pragma unroll
                    for (int j = 0; j < 4; ++j) {
                        int gcol = n0 + wn + j * 16 + fr;
                        O[(size_t)grow * N + gcol] =
                            acc[h][i][j][r] + bias0[gcol] + bias1[(size_t)grow * D_MODEL + gcol];
                    }
                }
    }
}

// ---------------- scan pass 1: per-chunk (A = prod sd, B = local scan) ----
// 4 channels/thread, 8B bf16x4 loads. CLEN=32 -> 512 blocks (2/CU).
__global__ __launch_bounds__(256) void scan_part1(
    const __hip_bfloat16* __restrict__ out1,
    float* __restrict__ Abuf, float* __restrict__ Bbuf)
{
    int g = blockIdx.x * 256 + threadIdx.x;  // NCHAN/4 * NCH = 131072
    int cg = g & 1023;                       // channel-group
    int c = g >> 10;                         // chunk 0..127
    int chan0 = cg * 4;
    int b = chan0 >> 10, hd0 = chan0 & 1023;
    size_t tok0 = (size_t)b * SEQ + (size_t)c * CLEN;
    const short* pd = (const short*)out1 + tok0 * N1 + D_MODEL + hd0;
    float a[4] = {1.f, 1.f, 1.f, 1.f};
    float hl[4] = {0.f, 0.f, 0.f, 0.f};
#pragma unroll 4
    for (int s = 0; s < CLEN; s++) {
        bf16x4 dv = *(const bf16x4*)pd;
        bf16x4 bv = *(const bf16x4*)(pd + 1024);
#pragma unroll
        for (int k = 0; k < 4; k++) {
            float sd = sigmoidf_(b2f(dv[k]));
            a[k] *= sd;
            hl[k] = sd * hl[k] + b2f(bv[k]);
        }
        pd += N1;
    }
    *(f32x4*)&Abuf[c * NCHAN + chan0] = (f32x4){a[0], a[1], a[2], a[3]};
    *(f32x4*)&Bbuf[c * NCHAN + chan0] = (f32x4){hl[0], hl[1], hl[2], hl[3]};
}

// ---------------- scan pass 2+3 fused: prescan combine + apply ----------
// In-place: mixed overwrites xn (1:1 element map, read-before-write per
// thread). Prescan: <=127 L2-resident f32x4-pair loads. Last-chunk
// threads write new_state.
__global__ __launch_bounds__(256) void scan_apply(
    const __hip_bfloat16* __restrict__ out1,
    __hip_bfloat16* xnm,                      // xn in, mixed out (aliased)
    const float* __restrict__ Abuf, const float* __restrict__ Bbuf,
    const float* __restrict__ state,
    float* __restrict__ new_state)
{
    int g = blockIdx.x * 256 + threadIdx.x;
    int cg = g & 1023;
    int c = g >> 10;
    int chan0 = cg * 4;
    int b = chan0 >> 10, hd0 = chan0 & 1023;
    size_t tok0 = (size_t)b * SEQ + (size_t)c * CLEN;

    f32x4 hp4 = *(const f32x4*)&state[chan0];
    for (int cc = 0; cc < c; ++cc) {
        f32x4 av = *(const f32x4*)&Abuf[cc * NCHAN + chan0];
        f32x4 bv = *(const f32x4*)&Bbuf[cc * NCHAN + chan0];
        hp4 = av * hp4 + bv;
    }
    float hp[4] = {hp4[0], hp4[1], hp4[2], hp4[3]};

    const short* rbase = (const short*)out1 + tok0 * N1;
    short* xb = (short*)xnm + tok0 * D_MODEL + hd0;
#pragma unroll 4
    for (int s = 0; s < CLEN; s++) {
        bf16x4 dv = *(const bf16x4*)(rbase + D_MODEL + hd0);
        bf16x4 bv = *(const bf16x4*)(rbase + 2048 + hd0);
        bf16x4 cv = *(const bf16x4*)(rbase + 3072 + hd0);
        bf16x4 gv = *(const bf16x4*)(rbase + hd0);
        bf16x4 xv = *(const bf16x4*)xb;
        bf16x4 ov;
#pragma unroll
        for (int k = 0; k < 4; k++) {
            float sd = sigmoidf_(b2f(dv[k]));
            hp[k] = sd * hp[k] + b2f(bv[k]);
            float gg = sigmoidf_(b2f(gv[k]));
            ov[k] = f2b(gg * (b2f(cv[k]) * hp[k]) + (1.0f - gg) * b2f(xv[k]));
        }
        *(bf16x4*)xb = ov;
        rbase += N1;
        xb += D_MODEL;
    }
    if (c == NCH - 1)
        *(f32x4*)&new_state[chan0] = (f32x4){hp[0], hp[1], hp[2], hp[3]};
}

extern "C" void kernel_launch(void* const* d_in, const int* in_sizes, int n_in,
                              void* d_out, int out_size, void* d_ws, size_t ws_size,
                              hipStream_t stream) {
    const float* x      = (const float*)d_in[0];
    const float* state  = (const float*)d_in[1];
    const float* norm_w = (const float*)d_in[2];
    const float* Wp     = (const float*)d_in[3];
    const float* bp     = (const float*)d_in[4];
    const float* Wg     = (const float*)d_in[5];
    const float* bg     = (const float*)d_in[6];
    const float* Wo     = (const float*)d_in[7];
    const float* bo     = (const float*)d_in[8];
    float* out = (float*)d_out;

    // workspace layout (~174 MB; mixed aliases xnb)
    __hip_bfloat16* W1T   = (__hip_bfloat16*)d_ws;                  // 4096 x 1024
    __hip_bfloat16* WoT   = W1T + (size_t)N1 * D_MODEL;             // 1024 x 1024
    __hip_bfloat16* xnb   = WoT + (size_t)D_MODEL * D_MODEL;        // 16384 x 1024
    __hip_bfloat16* out1  = xnb + (size_t)M_TOK * D_MODEL;          // 16384 x 4096
    float* Abuf = (float*)(out1 + (size_t)M_TOK * N1);              // 128 x 4096
    float* Bbuf = Abuf + (size_t)NCHAN * NCH;                       // 128 x 4096

    static bool attr_set = false;
    if (!attr_set) {
        hipFuncSetAttribute(reinterpret_cast<const void*>(&gemm256<0>),
                            hipFuncAttributeMaxDynamicSharedMemorySize, 131072);
        hipFuncSetAttribute(reinterpret_cast<const void*>(&gemm256<1>),
                            hipFuncAttributeMaxDynamicSharedMemorySize, 131072);
        attr_set = true;
    }

    prep_kernel<<<9216, 256, 0, stream>>>(
        Wg, Wp, Wo, x, norm_w, W1T, WoT, xnb);

    gemm256<0><<<dim3(N1 / 256, M_TOK / 256), 512, 131072, stream>>>(
        xnb, W1T, bg, bp, (void*)out1, N1, D_MODEL);

    scan_part1<<<(NCHAN / 4 * NCH) / 256, 256, 0, stream>>>(out1, Abuf, Bbuf);

    scan_apply<<<(NCHAN / 4 * NCH) / 256, 256, 0, stream>>>(
        out1, xnb, Abuf, Bbuf, state, out + (size_t)M_TOK * D_MODEL);

    gemm256<1><<<dim3(D_MODEL / 256, M_TOK / 256), 512, 131072, stream>>>(
        xnb, WoT, bo, x, (void*)out, D_MODEL, D_MODEL);
}

// Round 8
// 398.527 us; speedup vs baseline: 1.0055x; 1.0055x over previous
//
#include <hip/hip_runtime.h>
#include <hip/hip_bf16.h>
#include <cstdint>
#include <cstddef>

#define D_MODEL 1024
#define N_HEADS 16
#define D_STATE 64
#define SEQ 4096
#define BATCH 4
#define M_TOK (BATCH * SEQ)          // 16384 tokens
#define N1 4096                      // fused [Wg | p] output width
#define CLEN 32                      // scan chunk length
#define NCH (SEQ / CLEN)             // 128 chunks per sequence
#define NCHAN (BATCH * D_MODEL)      // 4096 scan channels

typedef __attribute__((ext_vector_type(8))) short bf16x8;
typedef __attribute__((ext_vector_type(4))) short bf16x4;
typedef __attribute__((ext_vector_type(4))) float f32x4;

__device__ __forceinline__ float sigmoidf_(float x) {
    return 1.0f / (1.0f + __expf(-x));
}
__device__ __forceinline__ float b2f(short s) {
    union { float f; unsigned u; } v; v.u = ((unsigned)(unsigned short)s) << 16;
    return v.f;
}
__device__ __forceinline__ short f2b(float f) {
    __hip_bfloat16 h = __float2bfloat16(f);
    return *(short*)&h;
}

__device__ __forceinline__ void async_load16(const void* g, void* l) {
    __builtin_amdgcn_global_load_lds(
        (__attribute__((address_space(1))) void*)(g),
        (__attribute__((address_space(3))) void*)(l), 16, 0, 0);
}

// ---------------- fused prep: 3 weight transposes + RMSNorm ----------------
// blocks [0,1024): Wg -> W1T rows 0..1023
// blocks [1024,4096): Wp -> W1T rows 1024..4095, col-permuted to block
//     layout: orig col n = h*192 + t*64 + d -> row 1024 + t*1024 + h*64 + d.
// blocks [4096,5120): Wo -> WoT
// blocks [5120,9216): rmsnorm, 4 rows/block, wave-per-row, 16 floats/lane.
__global__ __launch_bounds__(256) void prep_kernel(
    const float* __restrict__ Wg, const float* __restrict__ Wp,
    const float* __restrict__ Wo,
    const float* __restrict__ x, const float* __restrict__ norm_w,
    __hip_bfloat16* __restrict__ W1T, __hip_bfloat16* __restrict__ WoT,
    __hip_bfloat16* __restrict__ xn)
{
    __shared__ float tile[32][33];
    const int bid = blockIdx.x;
    const int tid = threadIdx.x;

    if (bid < 5120) {
        const float* src; __hip_bfloat16* dst; int N, bx, by, perm;
        if (bid < 1024)      { src = Wg; dst = W1T; N = 1024; bx = bid & 31;        by = bid >> 5;        perm = 0; }
        else if (bid < 4096) { int l = bid - 1024; src = Wp; dst = W1T; N = 3072; bx = l % 96; by = l / 96; perm = 1; }
        else                 { int l = bid - 4096; src = Wo; dst = WoT; N = 1024; bx = l & 31; by = l >> 5; perm = 0; }
        int n0 = bx * 32, k0 = by * 32;
        int tx = tid & 31, ty = tid >> 5;
#pragma unroll
        for (int j = 0; j < 32; j += 8)
            tile[ty + j][tx] = src[(size_t)(k0 + ty + j) * N + n0 + tx];
        __syncthreads();
#pragma unroll
        for (int j = 0; j < 32; j += 8) {
            int n = n0 + ty + j;
            int row;
            if (perm) {
                int ht = n >> 6;                  // h*3 + t
                row = 1024 + (ht % 3) * 1024 + (ht / 3) * 64 + (n & 63);
            } else row = n;
            dst[(size_t)row * D_MODEL + k0 + tx] = __float2bfloat16(tile[tx][ty + j]);
        }
    } else {
        int m = (bid - 5120) * 4 + (tid >> 6);
        int lane = tid & 63;
        const float4* xr = (const float4*)(x + (size_t)m * D_MODEL);
        float4 v[4];
        float ss = 0.f;
#pragma unroll
        for (int q = 0; q < 4; ++q) {
            v[q] = xr[lane + 64 * q];
            ss += v[q].x * v[q].x + v[q].y * v[q].y + v[q].z * v[q].z + v[q].w * v[q].w;
        }
#pragma unroll
        for (int o = 32; o >= 1; o >>= 1) ss += __shfl_xor(ss, o, 64);
        float scale = rsqrtf(ss * (1.0f / D_MODEL) + 1e-6f);
        const float4* wr = (const float4*)norm_w;
#pragma unroll
        for (int q = 0; q < 4; ++q) {
            float4 wv = wr[lane + 64 * q];
            __hip_bfloat16 o4[4];
            o4[0] = __float2bfloat16(wv.x * v[q].x * scale);
            o4[1] = __float2bfloat16(wv.y * v[q].y * scale);
            o4[2] = __float2bfloat16(wv.z * v[q].z * scale);
            o4[3] = __float2bfloat16(wv.w * v[q].w * scale);
            *(uint64_t*)(xn + (size_t)m * D_MODEL + (lane + 64 * q) * 4) = *(uint64_t*)o4;
        }
    }
}

// ---------------- 256x256 read-ahead pipelined bf16 MFMA GEMM ----------------
// REVERTED to the R4/R5 schedule (measured best: 139-140 us; R6/R7 deep
// staging was +6 us). Per tile t: 4 phases, stage 2 chunks/phase into the
// next buffer, two counted gates (vmcnt(4) at P1, vmcnt(2) at P3), per-wave
// read-ahead of next phase's fragments before each MFMA cluster.
// NEW (R8): moff param — gemm0 is launched as 4 M-slices of 4096 rows so
// each dispatch is ~36 us, letting tail kernels surface in the top-5
// profile (diagnostic for the ~130 us unexplained budget).
// T2 swizzle (0 conflicts), T1 XCD swizzle (per-slice nwg=256, %8==0),
// T5 setprio unchanged.
// MODE 0: out bf16, bias = (col<1024 ? bg[col] : bp[perm(col-1024)])
// MODE 1: out fp32, bias = bias0[col] + bias1[row*1024+col] (residual)
template <int MODE>
__global__ __launch_bounds__(512, 2) void gemm256(
    const __hip_bfloat16* __restrict__ A,
    const __hip_bfloat16* __restrict__ Bt,
    const float* __restrict__ bias0,
    const float* __restrict__ bias1,
    void* __restrict__ outp, int N, int K, int moff)
{
    extern __shared__ short lds[];
    const int tid = threadIdx.x;
    const int wave = tid >> 6, lane = tid & 63;
    const int fr = lane & 15, fq = lane >> 4;
    const int frx = fr & 7;
    const int wm = (wave >> 2) * 128;   // 2 M-halves of waves
    const int wn = (wave & 3) * 64;     // 4 N-quarters

    // bijective XCD swizzle (nwg % 8 == 0 for both modes)
    const int gx = gridDim.x;
    const int nwg = gx * gridDim.y;
    const int orig = blockIdx.y * gx + blockIdx.x;
    const int swz = (orig & 7) * (nwg >> 3) + (orig >> 3);
    const int m0 = (swz / gx) * 256 + moff;
    const int n0 = (swz % gx) * 256;

    // staging map: thread t -> row rb (8 threads/row), 16B slot p8.
    // global source slot pre-inverse-swizzled; LDS dest stays linear.
    const int rb = tid >> 3, p8 = tid & 7;
    const int lsl = p8 ^ (rb & 7);
    const short* Ag0 = (const short*)A + (size_t)(m0 + rb) * K + lsl * 8;
    const short* Bg0 = (const short*)Bt + (size_t)(n0 + rb) * K + lsl * 8;
    const int stL = rb * 64 + p8 * 8;

    // per-lane ds_read byte-address components
    const int laneA = (wm + fr) * 128;
    const int laneB = (wn + fr) * 128;
    const int F0 = (fq ^ frx) * 16;
    const int F1 = ((4 + fq) ^ frx) * 16;

    const int NT = K >> 6;              // K-tiles of 64

    f32x4 acc[2][4][4];
#pragma unroll
    for (int h = 0; h < 2; ++h)
#pragma unroll
        for (int i = 0; i < 4; ++i)
#pragma unroll
            for (int j = 0; j < 4; ++j)
                acc[h][i][j] = (f32x4){0.f, 0.f, 0.f, 0.f};

    // prologue: stage tile 0 -> buf0, issue order B0,B1,B2,B3,A0,A2,A1,A3
    {
        short* la = lds;
        short* lb = lds + 16384;
        async_load16(Bg0 + (size_t)(0 * 64) * K, lb + stL + 0 * 4096);
        async_load16(Bg0 + (size_t)(1 * 64) * K, lb + stL + 1 * 4096);
        async_load16(Bg0 + (size_t)(2 * 64) * K, lb + stL + 2 * 4096);
        async_load16(Bg0 + (size_t)(3 * 64) * K, lb + stL + 3 * 4096);
        async_load16(Ag0 + (size_t)(0 * 64) * K, la + stL + 0 * 4096);
        async_load16(Ag0 + (size_t)(2 * 64) * K, la + stL + 2 * 4096);
        async_load16(Ag0 + (size_t)(1 * 64) * K, la + stL + 1 * 4096);
        async_load16(Ag0 + (size_t)(3 * 64) * K, la + stL + 3 * 4096);
    }
    asm volatile("s_waitcnt vmcnt(2)" ::: "memory");  // b0..b3,a0,a2 landed
    __builtin_amdgcn_s_barrier();
    __builtin_amdgcn_sched_barrier(0);

#define RD(base, off) (*(const bf16x8*)((base) + (off)))
#define STAGE_A(c) async_load16(AgN + (size_t)((c) * 64) * K, laN + stL + (c) * 4096)
#define STAGE_B(c) async_load16(BgN + (size_t)((c) * 64) * K, lbN + stL + (c) * 4096)

    bf16x8 afA[4][2], afB[4][2], b0[2][2], b1[2][2];

    // initial reads tile 0 / P0: A-h0 + b0 (from buf0)
    {
        const char* bA0 = (const char*)lds + laneA + F0;
        const char* bA1 = (const char*)lds + laneA + F1;
        const char* bB0 = (const char*)(lds + 16384) + laneB + F0;
        const char* bB1 = (const char*)(lds + 16384) + laneB + F1;
#pragma unroll
        for (int i = 0; i < 4; ++i) { afA[i][0] = RD(bA0, i * 2048); afA[i][1] = RD(bA1, i * 2048); }
#pragma unroll
        for (int j = 0; j < 2; ++j) { b0[j][0] = RD(bB0, j * 2048); b0[j][1] = RD(bB1, j * 2048); }
    }

    for (int t = 0; t < NT; ++t) {
        const short* Ab = lds + ((t & 1) ? 32768 : 0);
        const short* Bb = Ab + 16384;
        short* laN = lds + ((t & 1) ? 0 : 32768);
        short* lbN = laN + 16384;
        const short* AgN = Ag0 + (size_t)(t + 1) * 64;
        const short* BgN = Bg0 + (size_t)(t + 1) * 64;
        const bool pf = (t + 1 < NT);
        const char* bA0 = (const char*)Ab + laneA + F0;
        const char* bA1 = (const char*)Ab + laneA + F1;
        const char* bB0 = (const char*)Bb + laneB + F0;
        const char* bB1 = (const char*)Bb + laneB + F1;

        // ---- P0: stage B0,B1(t+1) ; read b1(t) ; MFMA h0 x b0 ----
        if (pf) { STAGE_B(0); STAGE_B(1); }
#pragma unroll
        for (int j = 0; j < 2; ++j) { b1[j][0] = RD(bB0, (2 + j) * 2048); b1[j][1] = RD(bB1, (2 + j) * 2048); }
        __builtin_amdgcn_s_setprio(1);
#pragma unroll
        for (int i = 0; i < 4; ++i)
#pragma unroll
            for (int j = 0; j < 2; ++j) {
                acc[0][i][j] = __builtin_amdgcn_mfma_f32_16x16x32_bf16(afA[i][0], b0[j][0], acc[0][i][j], 0, 0, 0);
                acc[0][i][j] = __builtin_amdgcn_mfma_f32_16x16x32_bf16(afA[i][1], b0[j][1], acc[0][i][j], 0, 0, 0);
            }
        __builtin_amdgcn_s_setprio(0);
        __builtin_amdgcn_sched_barrier(0);

        // ---- P1: stage B2,B3(t+1) ; gate ; read afB(t) ; MFMA h0 x b1 ----
        if (pf) { STAGE_B(2); STAGE_B(3); }
        if (pf) { asm volatile("s_waitcnt vmcnt(4)" ::: "memory"); }  // a1,a3(t) landed
        else    { asm volatile("s_waitcnt vmcnt(0)" ::: "memory"); }
        __builtin_amdgcn_s_barrier();   // all waves' a1,a3 deposits visible
        __builtin_amdgcn_sched_barrier(0);
#pragma unroll
        for (int i = 0; i < 4; ++i) { afB[i][0] = RD(bA0, 8192 + i * 2048); afB[i][1] = RD(bA1, 8192 + i * 2048); }
        __builtin_amdgcn_s_setprio(1);
#pragma unroll
        for (int i = 0; i < 4; ++i)
#pragma unroll
            for (int j = 0; j < 2; ++j) {
                acc[0][i][2 + j] = __builtin_amdgcn_mfma_f32_16x16x32_bf16(afA[i][0], b1[j][0], acc[0][i][2 + j], 0, 0, 0);
                acc[0][i][2 + j] = __builtin_amdgcn_mfma_f32_16x16x32_bf16(afA[i][1], b1[j][1], acc[0][i][2 + j], 0, 0, 0);
            }
        __builtin_amdgcn_s_setprio(0);
        __builtin_amdgcn_sched_barrier(0);

        // ---- P2: stage A0,A2(t+1) ; MFMA h1 x b0 ----
        if (pf) { STAGE_A(0); STAGE_A(2); }
        __builtin_amdgcn_s_setprio(1);
#pragma unroll
        for (int i = 0; i < 4; ++i)
#pragma unroll
            for (int j = 0; j < 2; ++j) {
                acc[1][i][j] = __builtin_amdgcn_mfma_f32_16x16x32_bf16(afB[i][0], b0[j][0], acc[1][i][j], 0, 0, 0);
                acc[1][i][j] = __builtin_amdgcn_mfma_f32_16x16x32_bf16(afB[i][1], b0[j][1], acc[1][i][j], 0, 0, 0);
            }
        __builtin_amdgcn_s_setprio(0);
        __builtin_amdgcn_sched_barrier(0);

        // ---- P3: stage A1,A3(t+1) ; gate ; read-ahead afA/b0(t+1) ;
        //          MFMA h1 x b1 ----
        if (pf) {
            STAGE_A(1); STAGE_A(3);
            asm volatile("s_waitcnt vmcnt(2)" ::: "memory");  // t+1: b0..b3,a0,a2 landed
            __builtin_amdgcn_s_barrier();
            __builtin_amdgcn_sched_barrier(0);
            const char* nA0 = (const char*)laN + laneA + F0;
            const char* nA1 = (const char*)laN + laneA + F1;
            const char* nB0 = (const char*)lbN + laneB + F0;
            const char* nB1 = (const char*)lbN + laneB + F1;
#pragma unroll
            for (int i = 0; i < 4; ++i) { afA[i][0] = RD(nA0, i * 2048); afA[i][1] = RD(nA1, i * 2048); }
#pragma unroll
            for (int j = 0; j < 2; ++j) { b0[j][0] = RD(nB0, j * 2048); b0[j][1] = RD(nB1, j * 2048); }
        }
        __builtin_amdgcn_s_setprio(1);
#pragma unroll
        for (int i = 0; i < 4; ++i)
#pragma unroll
            for (int j = 0; j < 2; ++j) {
                acc[1][i][2 + j] = __builtin_amdgcn_mfma_f32_16x16x32_bf16(afB[i][0], b1[j][0], acc[1][i][2 + j], 0, 0, 0);
                acc[1][i][2 + j] = __builtin_amdgcn_mfma_f32_16x16x32_bf16(afB[i][1], b1[j][1], acc[1][i][2 + j], 0, 0, 0);
            }
        __builtin_amdgcn_s_setprio(0);
        __builtin_amdgcn_sched_barrier(0);
    }
#undef RD
#undef STAGE_A
#undef STAGE_B

    // epilogue: C/D layout row=fq*4+r, col=fr within 16x16 (m89-verified)
    if constexpr (MODE == 0) {
        __hip_bfloat16* O = (__hip_bfloat16*)outp;
        float bv[4];
#pragma unroll
        for (int j = 0; j < 4; ++j) {
            int gcol = n0 + wn + j * 16 + fr;
            if (gcol < D_MODEL) bv[j] = bias0[gcol];
            else {
                int q = gcol - D_MODEL;
                int tt = q >> 10, hd = q & 1023;
                bv[j] = bias1[(hd >> 6) * 192 + tt * 64 + (hd & 63)];
            }
        }
#pragma unroll
        for (int h = 0; h < 2; ++h)
#pragma unroll
            for (int i = 0; i < 4; ++i)
#pragma unroll
                for (int r = 0; r < 4; ++r) {
                    int grow = m0 + wm + h * 64 + i * 16 + fq * 4 + r;
                    __hip_bfloat16* orow = O + (size_t)grow * N + n0 + wn + fr;
#pragma unroll
                    for (int j = 0; j < 4; ++j)
                        orow[j * 16] = __float2bfloat16(acc[h][i][j][r] + bv[j]);
                }
    } else {
        float* O = (float*)outp;
#pragma unroll
        for (int h = 0; h < 2; ++h)
#pragma unroll
            for (int i = 0; i < 4; ++i)
#pragma unroll
                for (int r = 0; r < 4; ++r) {
                    int grow = m0 + wm + h * 64 + i * 16 + fq * 4 + r;
#pragma unroll
                    for (int j = 0; j < 4; ++j) {
                        int gcol = n0 + wn + j * 16 + fr;
                        O[(size_t)grow * N + gcol] =
                            acc[h][i][j][r] + bias0[gcol] + bias1[(size_t)grow * D_MODEL + gcol];
                    }
                }
    }
}

// ---------------- scan pass 1: per-chunk (A = prod sd, B = local scan) ----
// 4 channels/thread, 8B bf16x4 loads. CLEN=32 -> 512 blocks (2/CU).
__global__ __launch_bounds__(256) void scan_part1(
    const __hip_bfloat16* __restrict__ out1,
    float* __restrict__ Abuf, float* __restrict__ Bbuf)
{
    int g = blockIdx.x * 256 + threadIdx.x;  // NCHAN/4 * NCH = 131072
    int cg = g & 1023;                       // channel-group
    int c = g >> 10;                         // chunk 0..127
    int chan0 = cg * 4;
    int b = chan0 >> 10, hd0 = chan0 & 1023;
    size_t tok0 = (size_t)b * SEQ + (size_t)c * CLEN;
    const short* pd = (const short*)out1 + tok0 * N1 + D_MODEL + hd0;
    float a[4] = {1.f, 1.f, 1.f, 1.f};
    float hl[4] = {0.f, 0.f, 0.f, 0.f};
#pragma unroll 4
    for (int s = 0; s < CLEN; s++) {
        bf16x4 dv = *(const bf16x4*)pd;
        bf16x4 bv = *(const bf16x4*)(pd + 1024);
#pragma unroll
        for (int k = 0; k < 4; k++) {
            float sd = sigmoidf_(b2f(dv[k]));
            a[k] *= sd;
            hl[k] = sd * hl[k] + b2f(bv[k]);
        }
        pd += N1;
    }
    *(f32x4*)&Abuf[c * NCHAN + chan0] = (f32x4){a[0], a[1], a[2], a[3]};
    *(f32x4*)&Bbuf[c * NCHAN + chan0] = (f32x4){hl[0], hl[1], hl[2], hl[3]};
}

// ---------------- scan pass 2+3 fused: prescan combine + apply ----------
// In-place: mixed overwrites xn (1:1 element map, read-before-write per
// thread). Prescan: <=127 L2-resident f32x4-pair loads. Last-chunk
// threads write new_state.
__global__ __launch_bounds__(256) void scan_apply(
    const __hip_bfloat16* __restrict__ out1,
    __hip_bfloat16* xnm,                      // xn in, mixed out (aliased)
    const float* __restrict__ Abuf, const float* __restrict__ Bbuf,
    const float* __restrict__ state,
    float* __restrict__ new_state)
{
    int g = blockIdx.x * 256 + threadIdx.x;
    int cg = g & 1023;
    int c = g >> 10;
    int chan0 = cg * 4;
    int b = chan0 >> 10, hd0 = chan0 & 1023;
    size_t tok0 = (size_t)b * SEQ + (size_t)c * CLEN;

    f32x4 hp4 = *(const f32x4*)&state[chan0];
    for (int cc = 0; cc < c; ++cc) {
        f32x4 av = *(const f32x4*)&Abuf[cc * NCHAN + chan0];
        f32x4 bv = *(const f32x4*)&Bbuf[cc * NCHAN + chan0];
        hp4 = av * hp4 + bv;
    }
    float hp[4] = {hp4[0], hp4[1], hp4[2], hp4[3]};

    const short* rbase = (const short*)out1 + tok0 * N1;
    short* xb = (short*)xnm + tok0 * D_MODEL + hd0;
#pragma unroll 4
    for (int s = 0; s < CLEN; s++) {
        bf16x4 dv = *(const bf16x4*)(rbase + D_MODEL + hd0);
        bf16x4 bv = *(const bf16x4*)(rbase + 2048 + hd0);
        bf16x4 cv = *(const bf16x4*)(rbase + 3072 + hd0);
        bf16x4 gv = *(const bf16x4*)(rbase + hd0);
        bf16x4 xv = *(const bf16x4*)xb;
        bf16x4 ov;
#pragma unroll
        for (int k = 0; k < 4; k++) {
            float sd = sigmoidf_(b2f(dv[k]));
            hp[k] = sd * hp[k] + b2f(bv[k]);
            float gg = sigmoidf_(b2f(gv[k]));
            ov[k] = f2b(gg * (b2f(cv[k]) * hp[k]) + (1.0f - gg) * b2f(xv[k]));
        }
        *(bf16x4*)xb = ov;
        rbase += N1;
        xb += D_MODEL;
    }
    if (c == NCH - 1)
        *(f32x4*)&new_state[chan0] = (f32x4){hp[0], hp[1], hp[2], hp[3]};
}

extern "C" void kernel_launch(void* const* d_in, const int* in_sizes, int n_in,
                              void* d_out, int out_size, void* d_ws, size_t ws_size,
                              hipStream_t stream) {
    const float* x      = (const float*)d_in[0];
    const float* state  = (const float*)d_in[1];
    const float* norm_w = (const float*)d_in[2];
    const float* Wp     = (const float*)d_in[3];
    const float* bp     = (const float*)d_in[4];
    const float* Wg     = (const float*)d_in[5];
    const float* bg     = (const float*)d_in[6];
    const float* Wo     = (const float*)d_in[7];
    const float* bo     = (const float*)d_in[8];
    float* out = (float*)d_out;

    // workspace layout (~174 MB; mixed aliases xnb)
    __hip_bfloat16* W1T   = (__hip_bfloat16*)d_ws;                  // 4096 x 1024
    __hip_bfloat16* WoT   = W1T + (size_t)N1 * D_MODEL;             // 1024 x 1024
    __hip_bfloat16* xnb   = WoT + (size_t)D_MODEL * D_MODEL;        // 16384 x 1024
    __hip_bfloat16* out1  = xnb + (size_t)M_TOK * D_MODEL;          // 16384 x 4096
    float* Abuf = (float*)(out1 + (size_t)M_TOK * N1);              // 128 x 4096
    float* Bbuf = Abuf + (size_t)NCHAN * NCH;                       // 128 x 4096

    static bool attr_set = false;
    if (!attr_set) {
        hipFuncSetAttribute(reinterpret_cast<const void*>(&gemm256<0>),
                            hipFuncAttributeMaxDynamicSharedMemorySize, 131072);
        hipFuncSetAttribute(reinterpret_cast<const void*>(&gemm256<1>),
                            hipFuncAttributeMaxDynamicSharedMemorySize, 131072);
        attr_set = true;
    }

    prep_kernel<<<9216, 256, 0, stream>>>(
        Wg, Wp, Wo, x, norm_w, W1T, WoT, xnb);

    // gemm0 split into 4 M-slices (~36 us each): diagnostic so tail
    // kernels can surface in the top-5 profile. Slices are independent
    // (disjoint M rows) and queue back-to-back on the stream.
    for (int s = 0; s < 4; ++s)
        gemm256<0><<<dim3(N1 / 256, 16), 512, 131072, stream>>>(
            xnb, W1T, bg, bp, (void*)out1, N1, D_MODEL, s * 4096);

    scan_part1<<<(NCHAN / 4 * NCH) / 256, 256, 0, stream>>>(out1, Abuf, Bbuf);

    scan_apply<<<(NCHAN / 4 * NCH) / 256, 256, 0, stream>>>(
        out1, xnb, Abuf, Bbuf, state, out + (size_t)M_TOK * D_MODEL);

    gemm256<1><<<dim3(D_MODEL / 256, M_TOK / 256), 512, 131072, stream>>>(
        xnb, WoT, bo, x, (void*)out, D_MODEL, D_MODEL, 0);
}